// Round 12
// baseline (274.939 us; speedup 1.0000x reference)
//
#include <hip/hip_runtime.h>
#include <math.h>

// ---------------------------------------------------------------------------
// RepirDet head forward, MI355X f32 implementation (round 12).
// Revert round-11 merge (z-partitioned k_mid was net-negative: no real
// co-residency + union-LDS + L2 thrash). Round-10 structure + lastup (256,4).
// ---------------------------------------------------------------------------

#define NSLOT 824  // padded per-batch active-list capacity (true max 819)

typedef __attribute__((ext_vector_type(4))) float f32x4;

struct __attribute__((packed, aligned(4))) f4u { float a0, a1, a2, a3; };

__device__ __forceinline__ void nt_store4(float* p, float a, float b, float c,
                                          float d) {
  f32x4 v = {a, b, c, d};
  __builtin_nontemporal_store(v, reinterpret_cast<f32x4*>(p));
}

__device__ __forceinline__ float erf_fast(float x) {
  float ax = fabsf(x);
  float t = __builtin_amdgcn_rcpf(fmaf(0.3275911f, ax, 1.f));
  float poly = t * fmaf(t, fmaf(t, fmaf(t, fmaf(t, 1.061405429f, -1.453152027f),
                                        1.421413741f), -0.284496736f), 0.254829592f);
  float r = 1.f - poly * __expf(-ax * ax);
  return copysignf(r, x);
}

__global__ void k_sig(const float* __restrict__ lg, float* __restrict__ out) {
  int i = blockIdx.x * 256 + threadIdx.x;
  float4 v = reinterpret_cast<const float4*>(lg)[i];
  nt_store4(out + (i << 2), 1.f / (1.f + __expf(-v.x)), 1.f / (1.f + __expf(-v.y)),
            1.f / (1.f + __expf(-v.z)), 1.f / (1.f + __expf(-v.w)));
}

// exact 819th-largest logit (radix select) + compact active-pixel list
__global__ __launch_bounds__(1024) void k_topk(const float* __restrict__ lg,
                                               int* __restrict__ actIdx,
                                               int* __restrict__ n_act) {
  __shared__ unsigned keys[16384];
  __shared__ unsigned hist[256];
  __shared__ unsigned sh_prefix, sh_krem;
  __shared__ int sh_cnt;
  int b = blockIdx.x, t = threadIdx.x;
  if (t < 256) hist[t] = 0u;
  if (t == 0) { sh_prefix = 0u; sh_krem = 819u; sh_cnt = 0; }
  __syncthreads();
  for (int i = t; i < 16384; i += 1024) {
    float vF = lg[(b << 16) + ((i >> 7) << 9) + ((i & 127) << 1)];
    unsigned u = __float_as_uint(vF);
    unsigned key = (u & 0x80000000u) ? ~u : (u | 0x80000000u);
    keys[i] = key;
    atomicAdd(&hist[key >> 24], 1u);
  }
  for (int pass = 0; pass < 4; ++pass) {
    __syncthreads();
    if (t == 0) {
      unsigned krem = sh_krem, c = 0;
      int bin = 255;
      for (; bin >= 0; --bin) {
        unsigned c2 = c + hist[bin];
        if (c2 >= krem) break;
        c = c2;
      }
      sh_prefix = (sh_prefix << 8) | (unsigned)bin;
      sh_krem = krem - c;
    }
    __syncthreads();
    if (pass < 3) {
      if (t < 256) hist[t] = 0u;
      __syncthreads();
      int shift = 16 - 8 * pass;
      unsigned pref = sh_prefix;
      for (int i = t; i < 16384; i += 1024) {
        unsigned key = keys[i];
        if ((key >> (shift + 8)) == pref) atomicAdd(&hist[(key >> shift) & 255u], 1u);
      }
    }
  }
  __syncthreads();
  unsigned thrkey = sh_prefix;
  for (int i = t; i < 16384; i += 1024) {
    if (keys[i] > thrkey) {
      int s = atomicAdd(&sh_cnt, 1);
      actIdx[b * NSLOT + s] = i;
    }
  }
  __syncthreads();
  if (t == 0) n_act[b] = sh_cnt;
}

// sparse dw7x7 + LN + pw1 + gelu on active pixels.
__global__ __launch_bounds__(256, 4) void k_dws(
    const float* __restrict__ f4, const int* __restrict__ actIdx,
    const int* __restrict__ n_act, const float* __restrict__ dw_w,
    const float* __restrict__ dw_b, const float* __restrict__ lng,
    const float* __restrict__ lnb, const float* __restrict__ w1,
    const float* __restrict__ b1, float* __restrict__ y1c,
    float* __restrict__ gss) {
  int b = blockIdx.y;
  int slot0 = blockIdx.x << 3;
  int na = n_act[b];
  if (slot0 >= na) return;
  int t = threadIdx.x;
  __shared__ float wdwT[49][32];   // [tap][c]
  __shared__ float w1sT[32][32];   // [c][j]
  __shared__ float xhs[8][32];
  __shared__ float pacc[8][32];
  __shared__ float sLng[32], sLnb[32], sB1[32], sDwB[32];
  for (int i = t; i < 1568; i += 256) wdwT[i % 49][i / 49] = dw_w[i];
  for (int i = t; i < 1024; i += 256) w1sT[i & 31][i >> 5] = w1[i];
  if (t < 32) { sLng[t] = lng[t]; sLnb[t] = lnb[t]; sB1[t] = b1[t]; sDwB[t] = dw_b[t]; }
  __syncthreads();
  int px = t >> 5, c = t & 31;
  int slot = slot0 + px;
  bool valid = slot < na;
  int pos = valid ? actIdx[b * NSLOT + slot] : -1;
  float xv = 0.f;
  if (valid) {
    int y = pos >> 7, x = pos & 127;
    const float* base = f4 + (((b << 5) + c) << 14);
    float a = sDwB[c];
    bool inner = (x >= 3) && (x <= 123);
#pragma unroll
    for (int dy = -3; dy <= 3; ++dy) {
      int yy = y + dy;
      if ((unsigned)yy < 128u) {
        const float* rp = base + (yy << 7) + x;
        if (inner) {
          f4u A4 = *reinterpret_cast<const f4u*>(rp - 3);
          f4u B4 = *reinterpret_cast<const f4u*>(rp + 1);
          float r[7] = {A4.a0, A4.a1, A4.a2, A4.a3, B4.a0, B4.a1, B4.a2};
#pragma unroll
          for (int k = 0; k < 7; ++k)
            a = fmaf(r[k], wdwT[(dy + 3) * 7 + k][c], a);
        } else {
#pragma unroll
          for (int k = 0; k < 7; ++k) {
            int xx = x - 3 + k;
            if ((unsigned)xx < 128u)
              a = fmaf(rp[k - 3], wdwT[(dy + 3) * 7 + k][c], a);
          }
        }
      }
    }
    xv = a;
  }
  float s1 = xv, s2 = xv * xv;
#pragma unroll
  for (int m = 1; m < 32; m <<= 1) {
    s1 += __shfl_xor(s1, m, 64);
    s2 += __shfl_xor(s2, m, 64);
  }
  float mu = s1 * 0.03125f;
  float var = fmaxf(s2 * 0.03125f - mu * mu, 0.f);
  float rs = rsqrtf(var + 1e-6f);
  float xh = (xv - mu) * rs * sLng[c] + sLnb[c];
  xhs[px][c] = valid ? xh : 0.f;
  __syncthreads();
  int j = c;
  float a = sB1[j];
#pragma unroll
  for (int cc = 0; cc < 32; ++cc) a = fmaf(xhs[px][cc], w1sT[cc][j], a);
  float gl = 0.5f * a * (1.f + erf_fast(a * 0.70710678f));
  pacc[px][j] = valid ? gl * gl : 0.f;
  if (valid) y1c[(b * NSLOT + slot) * 32 + j] = gl;
  __syncthreads();
  if (t < 32) {
    float s = 0.f;
#pragma unroll
    for (int q = 0; q < 8; ++q) s += pacc[q][t];
    atomicAdd(&gss[(b << 5) + t], s);
  }
}

// fold GRN into pw2 (with analytic masked-pixel constant) + Kconst
__global__ void k_grn(const float* __restrict__ gss, const int* __restrict__ n_act,
                      const float* __restrict__ grng, const float* __restrict__ grnb,
                      const float* __restrict__ w2, const float* __restrict__ b2,
                      const float* __restrict__ b1, float* __restrict__ w2sT,
                      float* __restrict__ bias2, float* __restrict__ Kconst) {
  int b = blockIdx.x, t = threadIdx.x;
  __shared__ float gxs[32], sc[32], gb1[32];
  if (t < 32) {
    float u = b1[t];
    float gl = 0.5f * u * (1.f + erf_fast(u * 0.70710678f));
    gb1[t] = gl;
    float cnt = (float)(16384 - n_act[b]);
    gxs[t] = sqrtf(gss[(b << 5) + t] + cnt * gl * gl);
  }
  __syncthreads();
  if (t < 32) {
    float m = 0.f;
#pragma unroll
    for (int c = 0; c < 32; ++c) m += gxs[c];
    m = m * 0.03125f + 1e-6f;
    sc[t] = grng[t] * (gxs[t] / m) + 1.f;
  }
  __syncthreads();
  for (int i = t; i < 1024; i += 256) {
    int c = i >> 5, j = i & 31;
    w2sT[(b << 10) + i] = w2[j * 32 + c] * sc[c];
  }
  if (t < 32) {
    float s = 0.f;
#pragma unroll
    for (int c = 0; c < 32; ++c) s += grnb[c] * w2[t * 32 + c];
    float bb = s + b2[t];
    bias2[(b << 5) + t] = bb;
    float k = bb;
#pragma unroll
    for (int c = 0; c < 32; ++c) k = fmaf(gb1[c] * sc[c], w2[t * 32 + c], k);
    Kconst[(b << 5) + t] = k;
  }
}

// sparse pw2: xact[slot][32] = f4[pos] + y1c @ W2s + bias2  (absolute value)
__global__ __launch_bounds__(256, 4) void k_pw2s(
    const float* __restrict__ y1c, const int* __restrict__ actIdx,
    const int* __restrict__ n_act, const float* __restrict__ w2sT,
    const float* __restrict__ bias2, const float* __restrict__ f4,
    float* __restrict__ xact) {
  int b = blockIdx.y;
  int slot0 = blockIdx.x << 3;
  int na = n_act[b];
  if (slot0 >= na) return;
  int t = threadIdx.x;
  __shared__ float w2s[32][32];  // [c][j]
  __shared__ float ys[8][32];
  __shared__ float sb2[32];
  for (int i = t; i < 1024; i += 256) w2s[i >> 5][i & 31] = w2sT[(b << 10) + i];
  if (t < 32) sb2[t] = bias2[(b << 5) + t];
  int px = t >> 5, j = t & 31;
  int slot = slot0 + px;
  bool valid = slot < na;
  ys[px][j] = valid ? y1c[(b * NSLOT + slot) * 32 + j] : 0.f;
  __syncthreads();
  if (valid) {
    int pos = actIdx[b * NSLOT + slot];
    float a = sb2[j];
#pragma unroll
    for (int cc = 0; cc < 32; ++cc) a = fmaf(ys[px][cc], w2s[cc][j], a);
    a += f4[(((b << 5) + j) << 14) + pos];
    xact[(b * NSLOT + slot) * 32 + j] = a;
  }
}

// FUSED dense pw2 (f4 + Kconst, sparse overwrite from xact) + 3x3 conv + bn1
// -> E (NHWC8, 128^2).  16x16 tile, grid (8,8,16).
__global__ __launch_bounds__(256, 4) void k_upconv(
    const float* __restrict__ f4, const float* __restrict__ Kc,
    const float* __restrict__ xact, const int* __restrict__ actIdx,
    const int* __restrict__ n_act, const float* __restrict__ wgt,
    const float* __restrict__ bias, const float* __restrict__ bng,
    const float* __restrict__ bnb, const float* __restrict__ bnm,
    const float* __restrict__ bnv, float* __restrict__ out) {
  int bx = blockIdx.x << 4, by = blockIdx.y << 4, b = blockIdx.z;
  int t = threadIdx.x;
  __shared__ __align__(16) float4 xt[18 * 19];
  __shared__ __align__(16) float4 wt[576];
  __shared__ unsigned short slotmap[324];
  __shared__ float sKc[32];
  for (int idx = t; idx < 576; idx += 256) {
    int g = idx / 72, rem = idx - g * 72;
    int tap = rem >> 3, o = rem & 7;
    int ky = tap / 3, kx = tap - ky * 3;
    float4 wv;
    wv.x = wgt[((o * 32 + g * 4 + 0) * 3 + ky) * 3 + kx];
    wv.y = wgt[((o * 32 + g * 4 + 1) * 3 + ky) * 3 + kx];
    wv.z = wgt[((o * 32 + g * 4 + 2) * 3 + ky) * 3 + kx];
    wv.w = wgt[((o * 32 + g * 4 + 3) * 3 + ky) * 3 + kx];
    wt[idx] = wv;
  }
  if (t < 32) sKc[t] = Kc[(b << 5) + t];
  for (int i = t; i < 324; i += 256) slotmap[i] = 0xFFFFu;
  __syncthreads();
  int na = n_act[b];
  for (int i = t; i < na; i += 256) {
    int pos = actIdx[b * NSLOT + i];
    int y = pos >> 7, x = pos & 127;
    unsigned r = (unsigned)(y - by + 1), c = (unsigned)(x - bx + 1);
    if (r < 18u && c < 18u) slotmap[r * 18 + c] = (unsigned short)i;
  }
  __syncthreads();
  int py = t >> 4, px = t & 15;
  float acc[8];
#pragma unroll
  for (int o = 0; o < 8; ++o) acc[o] = 0.f;
  float4 sr[2];
  auto loadg = [&](int g) {
#pragma unroll
    for (int k = 0; k < 2; ++k) {
      int i = t + (k << 8);
      float4 v = make_float4(0.f, 0.f, 0.f, 0.f);
      if (i < 324) {
        int r = i / 18, c = i - r * 18;
        int gy = by - 1 + r, gx = bx - 1 + c;
        if ((unsigned)gy < 128u && (unsigned)gx < 128u) {
          unsigned short s = slotmap[r * 18 + c];
          if (s != 0xFFFFu) {
            v = *reinterpret_cast<const float4*>(
                xact + ((b * NSLOT + (int)s) << 5) + (g << 2));
          } else {
            const float* p0 = f4 + (((b << 5) + (g << 2)) << 14) + (gy << 7) + gx;
            v.x = p0[0] + sKc[(g << 2) + 0];
            v.y = p0[16384] + sKc[(g << 2) + 1];
            v.z = p0[32768] + sKc[(g << 2) + 2];
            v.w = p0[49152] + sKc[(g << 2) + 3];
          }
        }
      }
      sr[k] = v;
    }
  };
  auto writeg = [&]() {
#pragma unroll
    for (int k = 0; k < 2; ++k) {
      int i = t + (k << 8);
      if (i < 324) {
        int r = i / 18;
        xt[r * 19 + (i - r * 18)] = sr[k];
      }
    }
  };
  loadg(0);
#pragma unroll 1
  for (int g = 0; g < 8; ++g) {
    writeg();
    __syncthreads();
    if (g < 7) loadg(g + 1);
#pragma unroll
    for (int ky = 0; ky < 3; ++ky) {
      float4 xr[3];
#pragma unroll
      for (int q = 0; q < 3; ++q) xr[q] = xt[(py + ky) * 19 + px + q];
#pragma unroll
      for (int kx = 0; kx < 3; ++kx)
#pragma unroll
        for (int o = 0; o < 8; ++o) {
          float4 wv = wt[(g * 9 + ky * 3 + kx) * 8 + o];
          float4 xv = xr[kx];
          acc[o] = fmaf(xv.w, wv.w, fmaf(xv.z, wv.z, fmaf(xv.y, wv.y, fmaf(xv.x, wv.x, acc[o]))));
        }
    }
    __syncthreads();
  }
  int gy = by + py, gx = bx + px;
  float ov[8];
#pragma unroll
  for (int o = 0; o < 8; ++o) {
    float rs = rsqrtf(bnv[o] + 1e-5f) * bng[o];
    ov[o] = acc[o] * rs + (bias[o] - bnm[o]) * rs + bnb[o];
  }
  float* op = out + (((b << 14) + (gy << 7) + gx) << 3);
  *reinterpret_cast<float4*>(op) = make_float4(ov[0], ov[1], ov[2], ov[3]);
  *reinterpret_cast<float4*>(op + 4) = make_float4(ov[4], ov[5], ov[6], ov[7]);
}

// shortcut 3x3 conv + bn2 + relu, NCHW in (16 ch, 256^2), scalar staging.
__global__ __launch_bounds__(256, 4) void k_conv3s(
    const float* __restrict__ xin,
    const float* __restrict__ wgt, const float* __restrict__ bias,
    const float* __restrict__ bng, const float* __restrict__ bnb,
    const float* __restrict__ bnm, const float* __restrict__ bnv,
    float* __restrict__ out) {
  int bx = blockIdx.x << 5, by = blockIdx.y << 5, b = blockIdx.z;
  int t = threadIdx.x;
  int py = t >> 3, px0 = (t & 7) << 2;
  __shared__ __align__(16) float4 xt[34 * 35];
  __shared__ __align__(16) float4 wt[4 * 9 * 8];
  for (int idx = t; idx < 288; idx += 256) {
    int g = idx / 72, rem = idx - g * 72;
    int tap = rem >> 3, o = rem & 7;
    int ky = tap / 3, kx = tap - ky * 3;
    float4 wv;
    wv.x = wgt[((o * 16 + g * 4 + 0) * 3 + ky) * 3 + kx];
    wv.y = wgt[((o * 16 + g * 4 + 1) * 3 + ky) * 3 + kx];
    wv.z = wgt[((o * 16 + g * 4 + 2) * 3 + ky) * 3 + kx];
    wv.w = wgt[((o * 16 + g * 4 + 3) * 3 + ky) * 3 + kx];
    wt[idx] = wv;
  }
  float acc[4][8];
#pragma unroll
  for (int i = 0; i < 4; ++i)
#pragma unroll
    for (int o = 0; o < 8; ++o) acc[i][o] = 0.f;

  float4 sr[5];
  auto loadg = [&](int g) {
#pragma unroll
    for (int k = 0; k < 5; ++k) {
      int i = t + (k << 8);
      float4 v = make_float4(0.f, 0.f, 0.f, 0.f);
      if (i < 1156) {
        int r = i / 34, c = i - r * 34;
        int gy = by - 1 + r, gx = bx - 1 + c;
        if ((unsigned)gy < 256u && (unsigned)gx < 256u) {
          const float* p0 = xin + (((b * 16 + (g << 2)) << 8) + gy) * 256 + gx;
          v.x = p0[0]; v.y = p0[65536]; v.z = p0[131072]; v.w = p0[196608];
        }
      }
      sr[k] = v;
    }
  };
  auto writeg = [&]() {
#pragma unroll
    for (int k = 0; k < 5; ++k) {
      int i = t + (k << 8);
      if (i < 1156) {
        int r = i / 34;
        xt[r * 35 + (i - r * 34)] = sr[k];
      }
    }
  };

  loadg(0);
#pragma unroll 1
  for (int g = 0; g < 4; ++g) {
    writeg();
    __syncthreads();
    if (g < 3) loadg(g + 1);
#pragma unroll
    for (int ky = 0; ky < 3; ++ky) {
      float4 xr[6];
#pragma unroll
      for (int q = 0; q < 6; ++q) xr[q] = xt[(py + ky) * 35 + px0 + q];
#pragma unroll
      for (int kx = 0; kx < 3; ++kx)
#pragma unroll
        for (int o = 0; o < 8; ++o) {
          float4 wv = wt[(g * 9 + ky * 3 + kx) * 8 + o];
#pragma unroll
          for (int i = 0; i < 4; ++i) {
            float4 xv = xr[kx + i];
            acc[i][o] = fmaf(xv.w, wv.w, fmaf(xv.z, wv.z, fmaf(xv.y, wv.y, fmaf(xv.x, wv.x, acc[i][o]))));
          }
        }
    }
    __syncthreads();
  }
  float scl[8], sbs[8];
#pragma unroll
  for (int o = 0; o < 8; ++o) {
    float rs = rsqrtf(bnv[o] + 1e-5f) * bng[o];
    scl[o] = rs;
    sbs[o] = (bias[o] - bnm[o]) * rs + bnb[o];
  }
  int gy = by + py;
#pragma unroll
  for (int i = 0; i < 4; ++i) {
    int gx = bx + px0 + i;
    float ov[8];
#pragma unroll
    for (int o = 0; o < 8; ++o)
      ov[o] = fmaxf(acc[i][o] * scl[o] + sbs[o], 0.f);
    float* op = out + (((b << 16) + (gy << 8) + gx) << 3);
    *reinterpret_cast<float4*>(op) = make_float4(ov[0], ov[1], ov[2], ov[3]);
    *reinterpret_cast<float4*>(op + 4) = make_float4(ov[4], ov[5], ov[6], ov[7]);
  }
}

// last 3x3 conv: on-the-fly bilinear-2x of E (groups 0,1) + D (groups 2,3).
__global__ __launch_bounds__(256, 4) void k_lastup(
    const float* __restrict__ E, const float* __restrict__ D,
    const float* __restrict__ wgt, const float* __restrict__ bias,
    float* __restrict__ out) {
  int bx = blockIdx.x << 5, by = blockIdx.y << 5, b = blockIdx.z;
  int t = threadIdx.x;
  int py = t >> 3, px0 = (t & 7) << 2;
  __shared__ __align__(16) float4 et[19][22][2];
  __shared__ __align__(16) float4 xt[34 * 35];
  __shared__ __align__(16) float4 wt[144];
  for (int idx = t; idx < 144; idx += 256) {
    int g = idx / 36, rem = idx - g * 36;
    int tap = rem >> 2, o = rem & 3;
    int ky = tap / 3, kx = tap - ky * 3;
    float4 wv;
    wv.x = wgt[((o * 16 + g * 4 + 0) * 3 + ky) * 3 + kx];
    wv.y = wgt[((o * 16 + g * 4 + 1) * 3 + ky) * 3 + kx];
    wv.z = wgt[((o * 16 + g * 4 + 2) * 3 + ky) * 3 + kx];
    wv.w = wgt[((o * 16 + g * 4 + 3) * 3 + ky) * 3 + kx];
    wt[idx] = wv;
  }
  float acc[4][4];
#pragma unroll
  for (int i = 0; i < 4; ++i)
#pragma unroll
    for (int o = 0; o < 4; ++o) acc[i][o] = 0.f;

  float4 dreg[5];
  auto loadD = [&](int h) {
#pragma unroll
    for (int k = 0; k < 5; ++k) {
      int i = t + (k << 8);
      float4 v = make_float4(0.f, 0.f, 0.f, 0.f);
      if (i < 1156) {
        int r = i / 34, c = i - r * 34;
        int gy = by - 1 + r, gx = bx - 1 + c;
        if ((unsigned)gy < 256u && (unsigned)gx < 256u)
          v = *reinterpret_cast<const float4*>(
              D + (((b << 16) + (gy << 8) + gx) << 3) + (h << 2));
      }
      dreg[k] = v;
    }
  };
  auto compute = [&](int g) {
#pragma unroll
    for (int ky = 0; ky < 3; ++ky) {
      float4 xr[6];
#pragma unroll
      for (int q = 0; q < 6; ++q) xr[q] = xt[(py + ky) * 35 + px0 + q];
#pragma unroll
      for (int kx = 0; kx < 3; ++kx)
#pragma unroll
        for (int o = 0; o < 4; ++o) {
          float4 wv = wt[(g * 9 + ky * 3 + kx) * 4 + o];
#pragma unroll
          for (int i = 0; i < 4; ++i) {
            float4 xv = xr[kx + i];
            acc[i][o] = fmaf(xv.w, wv.w, fmaf(xv.z, wv.z, fmaf(xv.y, wv.y, fmaf(xv.x, wv.x, acc[i][o]))));
          }
        }
    }
  };

  loadD(0);
  int ey0 = (by >> 1) - 1, ex0 = (bx >> 1) - 3;
#pragma unroll
  for (int k = 0; k < 4; ++k) {
    int i = t + (k << 8);
    if (i < 836) {
      int h = i & 1, q = i >> 1;
      int r = q / 22, c = q - r * 22;
      int er = min(max(ey0 + r, 0), 127), ec = min(max(ex0 + c, 0), 127);
      et[r][c][h] = *reinterpret_cast<const float4*>(
          E + (((b << 14) + (er << 7) + ec) << 3) + (h << 2));
    }
  }
#pragma unroll 1
  for (int h = 0; h < 2; ++h) {
    __syncthreads();
#pragma unroll
    for (int k = 0; k < 5; ++k) {
      int i = t + (k << 8);
      if (i < 1156) {
        int r = i / 34;
        xt[r * 35 + (i - r * 34)] = dreg[k];
      }
    }
    __syncthreads();
    if (h == 0) loadD(1);
    compute(2 + h);
  }
#pragma unroll 1
  for (int h = 0; h < 2; ++h) {
    __syncthreads();
#pragma unroll
    for (int k = 0; k < 5; ++k) {
      int i = t + (k << 8);
      if (i < 1156) {
        int r = i / 34, c = i - r * 34;
        int gy = by - 1 + r, gx = bx - 1 + c;
        float4 uv = make_float4(0.f, 0.f, 0.f, 0.f);
        if ((unsigned)gy < 256u && (unsigned)gx < 256u) {
          int r0 = (gy - 1) >> 1, c0 = (gx - 1) >> 1;
          float fy = (gy & 1) ? 0.25f : 0.75f;
          float fx = (gx & 1) ? 0.25f : 0.75f;
          int ra = max(r0, 0) - ey0, rb = min(r0 + 1, 127) - ey0;
          int ca = max(c0, 0) - ex0, cb = min(c0 + 1, 127) - ex0;
          float w00 = (1.f - fy) * (1.f - fx), w01 = (1.f - fy) * fx;
          float w10 = fy * (1.f - fx), w11 = fy * fx;
          float4 a = et[ra][ca][h], bq = et[ra][cb][h];
          float4 cq = et[rb][ca][h], dq = et[rb][cb][h];
          uv.x = w00 * a.x + w01 * bq.x + w10 * cq.x + w11 * dq.x;
          uv.y = w00 * a.y + w01 * bq.y + w10 * cq.y + w11 * dq.y;
          uv.z = w00 * a.z + w01 * bq.z + w10 * cq.z + w11 * dq.z;
          uv.w = w00 * a.w + w01 * bq.w + w10 * cq.w + w11 * dq.w;
        }
        xt[r * 35 + c] = uv;
      }
    }
    __syncthreads();
    compute(h);
  }
  float b0 = bias[0], b1v = bias[1], b2v = bias[2], b3v = bias[3];
  int gy = by + py;
#pragma unroll
  for (int i = 0; i < 4; ++i) {
    int gx = bx + px0 + i;
    float* op = out + (((b << 16) + (gy << 8) + gx) << 2);
    *reinterpret_cast<float4*>(op) = make_float4(acc[i][0] + b0, acc[i][1] + b1v,
                                                 acc[i][2] + b2v, acc[i][3] + b3v);
  }
}

// bilinear 2x (256->512, zero outside) + 5x5 conv pad 2 + sigmoid -> out1
__global__ __launch_bounds__(256, 3) void k_final(
    const float* __restrict__ v4, const float* __restrict__ w5,
    const float* __restrict__ b5, float* __restrict__ out) {
  int bx = blockIdx.x << 5, by = blockIdx.y << 5, b = blockIdx.z;
  int t = threadIdx.x;
  __shared__ __align__(16) float4 vt[20 * 21];
  __shared__ __align__(16) float4 ut[36 * 37];
  __shared__ __align__(16) float4 w5s[25];
  if (t < 25) {
    w5s[t] = make_float4(w5[t], w5[25 + t], w5[50 + t], w5[75 + t]);
  }
  int vy0 = (by >> 1) - 2, vx0 = (bx >> 1) - 2;
  for (int i = t; i < 400; i += 256) {
    int r = i / 20, c = i - r * 20;
    int gy = vy0 + r, gx = vx0 + c;
    float4 v = make_float4(0.f, 0.f, 0.f, 0.f);
    if (gy >= 0 && gy < 256 && gx >= 0 && gx < 256)
      v = *reinterpret_cast<const float4*>(v4 + ((b << 16) + gy * 256 + gx) * 4);
    vt[r * 21 + c] = v;
  }
  __syncthreads();
  for (int i = t; i < 36 * 36; i += 256) {
    int r = i / 36, c = i - r * 36;
    int yy = by - 2 + r, xx = bx - 2 + c;
    float4 uv = make_float4(0.f, 0.f, 0.f, 0.f);
    if (yy >= 0 && yy < 512 && xx >= 0 && xx < 512) {
      int r0 = (yy - 1) >> 1, c0 = (xx - 1) >> 1;
      float fy = (yy & 1) ? 0.25f : 0.75f;
      float fx = (xx & 1) ? 0.25f : 0.75f;
      int ra = max(r0, 0) - vy0, rb = min(r0 + 1, 255) - vy0;
      int ca = max(c0, 0) - vx0, cb = min(c0 + 1, 255) - vx0;
      float4 a = vt[ra * 21 + ca], bq = vt[ra * 21 + cb];
      float4 cq = vt[rb * 21 + ca], dq = vt[rb * 21 + cb];
      float w00 = (1.f - fy) * (1.f - fx), w01 = (1.f - fy) * fx;
      float w10 = fy * (1.f - fx), w11 = fy * fx;
      uv.x = w00 * a.x + w01 * bq.x + w10 * cq.x + w11 * dq.x;
      uv.y = w00 * a.y + w01 * bq.y + w10 * cq.y + w11 * dq.y;
      uv.z = w00 * a.z + w01 * bq.z + w10 * cq.z + w11 * dq.z;
      uv.w = w00 * a.w + w01 * bq.w + w10 * cq.w + w11 * dq.w;
    }
    ut[r * 37 + c] = uv;
  }
  __syncthreads();
  float bb = b5[0];
  int py = t >> 3, px0 = (t & 7) << 2;
  float a0 = bb, a1 = bb, a2 = bb, a3 = bb;
#pragma unroll
  for (int ky = 0; ky < 5; ++ky) {
    float4 xr[8];
#pragma unroll
    for (int q = 0; q < 8; ++q) xr[q] = ut[(py + ky) * 37 + px0 + q];
#pragma unroll
    for (int kx = 0; kx < 5; ++kx) {
      float4 w = w5s[ky * 5 + kx];
      float4 x0 = xr[kx], x1 = xr[kx + 1], x2 = xr[kx + 2], x3 = xr[kx + 3];
      a0 = fmaf(x0.w, w.w, fmaf(x0.z, w.z, fmaf(x0.y, w.y, fmaf(x0.x, w.x, a0))));
      a1 = fmaf(x1.w, w.w, fmaf(x1.z, w.z, fmaf(x1.y, w.y, fmaf(x1.x, w.x, a1))));
      a2 = fmaf(x2.w, w.w, fmaf(x2.z, w.z, fmaf(x2.y, w.y, fmaf(x2.x, w.x, a2))));
      a3 = fmaf(x3.w, w.w, fmaf(x3.z, w.z, fmaf(x3.y, w.y, fmaf(x3.x, w.x, a3))));
    }
  }
  int oy = by + py, ox = bx + px0;
  nt_store4(out + (b << 18) + oy * 512 + ox,
            1.f / (1.f + __expf(-a0)), 1.f / (1.f + __expf(-a1)),
            1.f / (1.f + __expf(-a2)), 1.f / (1.f + __expf(-a3)));
}

extern "C" void kernel_launch(void* const* d_in, const int* in_sizes, int n_in,
                              void* d_out, int out_size, void* d_ws, size_t ws_size,
                              hipStream_t stream) {
  (void)in_sizes; (void)n_in; (void)out_size; (void)ws_size;
  const float* feats4x = (const float*)d_in[0];
  const float* feats2x = (const float*)d_in[1];
  const float* clg     = (const float*)d_in[2];
  const float* dw_w    = (const float*)d_in[3];
  const float* dw_b    = (const float*)d_in[4];
  const float* ln_g    = (const float*)d_in[5];
  const float* ln_b    = (const float*)d_in[6];
  const float* pw1_w   = (const float*)d_in[7];
  const float* pw1_b   = (const float*)d_in[8];
  const float* grn_g   = (const float*)d_in[9];
  const float* grn_b   = (const float*)d_in[10];
  const float* pw2_w   = (const float*)d_in[11];
  const float* pw2_b   = (const float*)d_in[12];
  const float* up_w    = (const float*)d_in[13];
  const float* up_b    = (const float*)d_in[14];
  const float* bn1_g   = (const float*)d_in[15];
  const float* bn1_b   = (const float*)d_in[16];
  const float* bn1_m   = (const float*)d_in[17];
  const float* bn1_v   = (const float*)d_in[18];
  const float* sh_w    = (const float*)d_in[19];
  const float* sh_b    = (const float*)d_in[20];
  const float* bn2_g   = (const float*)d_in[21];
  const float* bn2_b   = (const float*)d_in[22];
  const float* bn2_m   = (const float*)d_in[23];
  const float* bn2_v   = (const float*)d_in[24];
  const float* last_w  = (const float*)d_in[25];
  const float* last_b  = (const float*)d_in[26];
  const float* last2_w = (const float*)d_in[27];
  const float* last2_b = (const float*)d_in[28];
  float* outp = (float*)d_out;
  float* ws = (float*)d_ws;
  float* A      = ws;                      // lastup out (v4, 256^2)
  float* y1c    = ws + 8388608;            // 421888
  float* xact   = ws + 8810496;            // 421888
  int*   actIdx = (int*)(ws + 9232384);    // 13184
  int*   n_act  = (int*)(ws + 9245568);    // 16
  float* D      = ws + 16777216;           // shortcut branch (NHWC8 256^2)
  float* E      = ws + 25165824;           // up-conv out (NHWC8 128^2)
  float* gss    = ws + 27262976;           // 512
  float* w2sT   = gss + 512;               // 16384
  float* bias2  = w2sT + 16384;            // 512
  float* Kconst = bias2 + 512;             // 512

  hipMemsetAsync(gss, 0, 512 * sizeof(float), stream);
  k_sig<<<1024, 256, 0, stream>>>(clg, outp + 4194304);
  k_topk<<<16, 1024, 0, stream>>>(clg, actIdx, n_act);
  k_dws<<<dim3(103, 16), 256, 0, stream>>>(feats4x, actIdx, n_act, dw_w, dw_b,
                                           ln_g, ln_b, pw1_w, pw1_b, y1c, gss);
  k_grn<<<16, 256, 0, stream>>>(gss, n_act, grn_g, grn_b, pw2_w, pw2_b, pw1_b,
                                w2sT, bias2, Kconst);
  k_pw2s<<<dim3(103, 16), 256, 0, stream>>>(y1c, actIdx, n_act, w2sT, bias2,
                                            feats4x, xact);
  k_upconv<<<dim3(8, 8, 16), 256, 0, stream>>>(feats4x, Kconst, xact, actIdx,
                                               n_act, up_w, up_b, bn1_g, bn1_b,
                                               bn1_m, bn1_v, E);
  k_conv3s<<<dim3(8, 8, 16), 256, 0, stream>>>(feats2x, sh_w, sh_b, bn2_g,
                                               bn2_b, bn2_m, bn2_v, D);
  k_lastup<<<dim3(8, 8, 16), 256, 0, stream>>>(E, D, last_w, last_b, A);
  k_final<<<dim3(16, 16, 16), 256, 0, stream>>>(A, last2_w, last2_b, outp);
}

// Round 13
// 259.151 us; speedup vs baseline: 1.0609x; 1.0609x over previous
//
#include <hip/hip_runtime.h>
#include <math.h>

// ---------------------------------------------------------------------------
// RepirDet head forward, MI355X f32 implementation (round 13).
// Exact round-10 configuration (session best, 260.5 us): k_lastup reverted to
// (256,3) — VGPR-capped (256,4) cost ILP and regressed it 45->60 us.
// ---------------------------------------------------------------------------

#define NSLOT 824  // padded per-batch active-list capacity (true max 819)

typedef __attribute__((ext_vector_type(4))) float f32x4;

struct __attribute__((packed, aligned(4))) f4u { float a0, a1, a2, a3; };

__device__ __forceinline__ void nt_store4(float* p, float a, float b, float c,
                                          float d) {
  f32x4 v = {a, b, c, d};
  __builtin_nontemporal_store(v, reinterpret_cast<f32x4*>(p));
}

__device__ __forceinline__ float erf_fast(float x) {
  float ax = fabsf(x);
  float t = __builtin_amdgcn_rcpf(fmaf(0.3275911f, ax, 1.f));
  float poly = t * fmaf(t, fmaf(t, fmaf(t, fmaf(t, 1.061405429f, -1.453152027f),
                                        1.421413741f), -0.284496736f), 0.254829592f);
  float r = 1.f - poly * __expf(-ax * ax);
  return copysignf(r, x);
}

__global__ void k_sig(const float* __restrict__ lg, float* __restrict__ out) {
  int i = blockIdx.x * 256 + threadIdx.x;
  float4 v = reinterpret_cast<const float4*>(lg)[i];
  nt_store4(out + (i << 2), 1.f / (1.f + __expf(-v.x)), 1.f / (1.f + __expf(-v.y)),
            1.f / (1.f + __expf(-v.z)), 1.f / (1.f + __expf(-v.w)));
}

// exact 819th-largest logit (radix select) + compact active-pixel list
__global__ __launch_bounds__(1024) void k_topk(const float* __restrict__ lg,
                                               int* __restrict__ actIdx,
                                               int* __restrict__ n_act) {
  __shared__ unsigned keys[16384];
  __shared__ unsigned hist[256];
  __shared__ unsigned sh_prefix, sh_krem;
  __shared__ int sh_cnt;
  int b = blockIdx.x, t = threadIdx.x;
  if (t < 256) hist[t] = 0u;
  if (t == 0) { sh_prefix = 0u; sh_krem = 819u; sh_cnt = 0; }
  __syncthreads();
  for (int i = t; i < 16384; i += 1024) {
    float vF = lg[(b << 16) + ((i >> 7) << 9) + ((i & 127) << 1)];
    unsigned u = __float_as_uint(vF);
    unsigned key = (u & 0x80000000u) ? ~u : (u | 0x80000000u);
    keys[i] = key;
    atomicAdd(&hist[key >> 24], 1u);
  }
  for (int pass = 0; pass < 4; ++pass) {
    __syncthreads();
    if (t == 0) {
      unsigned krem = sh_krem, c = 0;
      int bin = 255;
      for (; bin >= 0; --bin) {
        unsigned c2 = c + hist[bin];
        if (c2 >= krem) break;
        c = c2;
      }
      sh_prefix = (sh_prefix << 8) | (unsigned)bin;
      sh_krem = krem - c;
    }
    __syncthreads();
    if (pass < 3) {
      if (t < 256) hist[t] = 0u;
      __syncthreads();
      int shift = 16 - 8 * pass;
      unsigned pref = sh_prefix;
      for (int i = t; i < 16384; i += 1024) {
        unsigned key = keys[i];
        if ((key >> (shift + 8)) == pref) atomicAdd(&hist[(key >> shift) & 255u], 1u);
      }
    }
  }
  __syncthreads();
  unsigned thrkey = sh_prefix;
  for (int i = t; i < 16384; i += 1024) {
    if (keys[i] > thrkey) {
      int s = atomicAdd(&sh_cnt, 1);
      actIdx[b * NSLOT + s] = i;
    }
  }
  __syncthreads();
  if (t == 0) n_act[b] = sh_cnt;
}

// sparse dw7x7 + LN + pw1 + gelu on active pixels.
__global__ __launch_bounds__(256, 4) void k_dws(
    const float* __restrict__ f4, const int* __restrict__ actIdx,
    const int* __restrict__ n_act, const float* __restrict__ dw_w,
    const float* __restrict__ dw_b, const float* __restrict__ lng,
    const float* __restrict__ lnb, const float* __restrict__ w1,
    const float* __restrict__ b1, float* __restrict__ y1c,
    float* __restrict__ gss) {
  int b = blockIdx.y;
  int slot0 = blockIdx.x << 3;
  int na = n_act[b];
  if (slot0 >= na) return;
  int t = threadIdx.x;
  __shared__ float wdwT[49][32];   // [tap][c]
  __shared__ float w1sT[32][32];   // [c][j]
  __shared__ float xhs[8][32];
  __shared__ float pacc[8][32];
  __shared__ float sLng[32], sLnb[32], sB1[32], sDwB[32];
  for (int i = t; i < 1568; i += 256) wdwT[i % 49][i / 49] = dw_w[i];
  for (int i = t; i < 1024; i += 256) w1sT[i & 31][i >> 5] = w1[i];
  if (t < 32) { sLng[t] = lng[t]; sLnb[t] = lnb[t]; sB1[t] = b1[t]; sDwB[t] = dw_b[t]; }
  __syncthreads();
  int px = t >> 5, c = t & 31;
  int slot = slot0 + px;
  bool valid = slot < na;
  int pos = valid ? actIdx[b * NSLOT + slot] : -1;
  float xv = 0.f;
  if (valid) {
    int y = pos >> 7, x = pos & 127;
    const float* base = f4 + (((b << 5) + c) << 14);
    float a = sDwB[c];
    bool inner = (x >= 3) && (x <= 123);
#pragma unroll
    for (int dy = -3; dy <= 3; ++dy) {
      int yy = y + dy;
      if ((unsigned)yy < 128u) {
        const float* rp = base + (yy << 7) + x;
        if (inner) {
          f4u A4 = *reinterpret_cast<const f4u*>(rp - 3);
          f4u B4 = *reinterpret_cast<const f4u*>(rp + 1);
          float r[7] = {A4.a0, A4.a1, A4.a2, A4.a3, B4.a0, B4.a1, B4.a2};
#pragma unroll
          for (int k = 0; k < 7; ++k)
            a = fmaf(r[k], wdwT[(dy + 3) * 7 + k][c], a);
        } else {
#pragma unroll
          for (int k = 0; k < 7; ++k) {
            int xx = x - 3 + k;
            if ((unsigned)xx < 128u)
              a = fmaf(rp[k - 3], wdwT[(dy + 3) * 7 + k][c], a);
          }
        }
      }
    }
    xv = a;
  }
  float s1 = xv, s2 = xv * xv;
#pragma unroll
  for (int m = 1; m < 32; m <<= 1) {
    s1 += __shfl_xor(s1, m, 64);
    s2 += __shfl_xor(s2, m, 64);
  }
  float mu = s1 * 0.03125f;
  float var = fmaxf(s2 * 0.03125f - mu * mu, 0.f);
  float rs = rsqrtf(var + 1e-6f);
  float xh = (xv - mu) * rs * sLng[c] + sLnb[c];
  xhs[px][c] = valid ? xh : 0.f;
  __syncthreads();
  int j = c;
  float a = sB1[j];
#pragma unroll
  for (int cc = 0; cc < 32; ++cc) a = fmaf(xhs[px][cc], w1sT[cc][j], a);
  float gl = 0.5f * a * (1.f + erf_fast(a * 0.70710678f));
  pacc[px][j] = valid ? gl * gl : 0.f;
  if (valid) y1c[(b * NSLOT + slot) * 32 + j] = gl;
  __syncthreads();
  if (t < 32) {
    float s = 0.f;
#pragma unroll
    for (int q = 0; q < 8; ++q) s += pacc[q][t];
    atomicAdd(&gss[(b << 5) + t], s);
  }
}

// fold GRN into pw2 (with analytic masked-pixel constant) + Kconst
__global__ void k_grn(const float* __restrict__ gss, const int* __restrict__ n_act,
                      const float* __restrict__ grng, const float* __restrict__ grnb,
                      const float* __restrict__ w2, const float* __restrict__ b2,
                      const float* __restrict__ b1, float* __restrict__ w2sT,
                      float* __restrict__ bias2, float* __restrict__ Kconst) {
  int b = blockIdx.x, t = threadIdx.x;
  __shared__ float gxs[32], sc[32], gb1[32];
  if (t < 32) {
    float u = b1[t];
    float gl = 0.5f * u * (1.f + erf_fast(u * 0.70710678f));
    gb1[t] = gl;
    float cnt = (float)(16384 - n_act[b]);
    gxs[t] = sqrtf(gss[(b << 5) + t] + cnt * gl * gl);
  }
  __syncthreads();
  if (t < 32) {
    float m = 0.f;
#pragma unroll
    for (int c = 0; c < 32; ++c) m += gxs[c];
    m = m * 0.03125f + 1e-6f;
    sc[t] = grng[t] * (gxs[t] / m) + 1.f;
  }
  __syncthreads();
  for (int i = t; i < 1024; i += 256) {
    int c = i >> 5, j = i & 31;
    w2sT[(b << 10) + i] = w2[j * 32 + c] * sc[c];
  }
  if (t < 32) {
    float s = 0.f;
#pragma unroll
    for (int c = 0; c < 32; ++c) s += grnb[c] * w2[t * 32 + c];
    float bb = s + b2[t];
    bias2[(b << 5) + t] = bb;
    float k = bb;
#pragma unroll
    for (int c = 0; c < 32; ++c) k = fmaf(gb1[c] * sc[c], w2[t * 32 + c], k);
    Kconst[(b << 5) + t] = k;
  }
}

// sparse pw2: xact[slot][32] = f4[pos] + y1c @ W2s + bias2  (absolute value)
__global__ __launch_bounds__(256, 4) void k_pw2s(
    const float* __restrict__ y1c, const int* __restrict__ actIdx,
    const int* __restrict__ n_act, const float* __restrict__ w2sT,
    const float* __restrict__ bias2, const float* __restrict__ f4,
    float* __restrict__ xact) {
  int b = blockIdx.y;
  int slot0 = blockIdx.x << 3;
  int na = n_act[b];
  if (slot0 >= na) return;
  int t = threadIdx.x;
  __shared__ float w2s[32][32];  // [c][j]
  __shared__ float ys[8][32];
  __shared__ float sb2[32];
  for (int i = t; i < 1024; i += 256) w2s[i >> 5][i & 31] = w2sT[(b << 10) + i];
  if (t < 32) sb2[t] = bias2[(b << 5) + t];
  int px = t >> 5, j = t & 31;
  int slot = slot0 + px;
  bool valid = slot < na;
  ys[px][j] = valid ? y1c[(b * NSLOT + slot) * 32 + j] : 0.f;
  __syncthreads();
  if (valid) {
    int pos = actIdx[b * NSLOT + slot];
    float a = sb2[j];
#pragma unroll
    for (int cc = 0; cc < 32; ++cc) a = fmaf(ys[px][cc], w2s[cc][j], a);
    a += f4[(((b << 5) + j) << 14) + pos];
    xact[(b * NSLOT + slot) * 32 + j] = a;
  }
}

// FUSED dense pw2 (f4 + Kconst, sparse overwrite from xact) + 3x3 conv + bn1
// -> E (NHWC8, 128^2).  16x16 tile, grid (8,8,16).
__global__ __launch_bounds__(256, 4) void k_upconv(
    const float* __restrict__ f4, const float* __restrict__ Kc,
    const float* __restrict__ xact, const int* __restrict__ actIdx,
    const int* __restrict__ n_act, const float* __restrict__ wgt,
    const float* __restrict__ bias, const float* __restrict__ bng,
    const float* __restrict__ bnb, const float* __restrict__ bnm,
    const float* __restrict__ bnv, float* __restrict__ out) {
  int bx = blockIdx.x << 4, by = blockIdx.y << 4, b = blockIdx.z;
  int t = threadIdx.x;
  __shared__ __align__(16) float4 xt[18 * 19];
  __shared__ __align__(16) float4 wt[576];
  __shared__ unsigned short slotmap[324];
  __shared__ float sKc[32];
  for (int idx = t; idx < 576; idx += 256) {
    int g = idx / 72, rem = idx - g * 72;
    int tap = rem >> 3, o = rem & 7;
    int ky = tap / 3, kx = tap - ky * 3;
    float4 wv;
    wv.x = wgt[((o * 32 + g * 4 + 0) * 3 + ky) * 3 + kx];
    wv.y = wgt[((o * 32 + g * 4 + 1) * 3 + ky) * 3 + kx];
    wv.z = wgt[((o * 32 + g * 4 + 2) * 3 + ky) * 3 + kx];
    wv.w = wgt[((o * 32 + g * 4 + 3) * 3 + ky) * 3 + kx];
    wt[idx] = wv;
  }
  if (t < 32) sKc[t] = Kc[(b << 5) + t];
  for (int i = t; i < 324; i += 256) slotmap[i] = 0xFFFFu;
  __syncthreads();
  int na = n_act[b];
  for (int i = t; i < na; i += 256) {
    int pos = actIdx[b * NSLOT + i];
    int y = pos >> 7, x = pos & 127;
    unsigned r = (unsigned)(y - by + 1), c = (unsigned)(x - bx + 1);
    if (r < 18u && c < 18u) slotmap[r * 18 + c] = (unsigned short)i;
  }
  __syncthreads();
  int py = t >> 4, px = t & 15;
  float acc[8];
#pragma unroll
  for (int o = 0; o < 8; ++o) acc[o] = 0.f;
  float4 sr[2];
  auto loadg = [&](int g) {
#pragma unroll
    for (int k = 0; k < 2; ++k) {
      int i = t + (k << 8);
      float4 v = make_float4(0.f, 0.f, 0.f, 0.f);
      if (i < 324) {
        int r = i / 18, c = i - r * 18;
        int gy = by - 1 + r, gx = bx - 1 + c;
        if ((unsigned)gy < 128u && (unsigned)gx < 128u) {
          unsigned short s = slotmap[r * 18 + c];
          if (s != 0xFFFFu) {
            v = *reinterpret_cast<const float4*>(
                xact + ((b * NSLOT + (int)s) << 5) + (g << 2));
          } else {
            const float* p0 = f4 + (((b << 5) + (g << 2)) << 14) + (gy << 7) + gx;
            v.x = p0[0] + sKc[(g << 2) + 0];
            v.y = p0[16384] + sKc[(g << 2) + 1];
            v.z = p0[32768] + sKc[(g << 2) + 2];
            v.w = p0[49152] + sKc[(g << 2) + 3];
          }
        }
      }
      sr[k] = v;
    }
  };
  auto writeg = [&]() {
#pragma unroll
    for (int k = 0; k < 2; ++k) {
      int i = t + (k << 8);
      if (i < 324) {
        int r = i / 18;
        xt[r * 19 + (i - r * 18)] = sr[k];
      }
    }
  };
  loadg(0);
#pragma unroll 1
  for (int g = 0; g < 8; ++g) {
    writeg();
    __syncthreads();
    if (g < 7) loadg(g + 1);
#pragma unroll
    for (int ky = 0; ky < 3; ++ky) {
      float4 xr[3];
#pragma unroll
      for (int q = 0; q < 3; ++q) xr[q] = xt[(py + ky) * 19 + px + q];
#pragma unroll
      for (int kx = 0; kx < 3; ++kx)
#pragma unroll
        for (int o = 0; o < 8; ++o) {
          float4 wv = wt[(g * 9 + ky * 3 + kx) * 8 + o];
          float4 xv = xr[kx];
          acc[o] = fmaf(xv.w, wv.w, fmaf(xv.z, wv.z, fmaf(xv.y, wv.y, fmaf(xv.x, wv.x, acc[o]))));
        }
    }
    __syncthreads();
  }
  int gy = by + py, gx = bx + px;
  float ov[8];
#pragma unroll
  for (int o = 0; o < 8; ++o) {
    float rs = rsqrtf(bnv[o] + 1e-5f) * bng[o];
    ov[o] = acc[o] * rs + (bias[o] - bnm[o]) * rs + bnb[o];
  }
  float* op = out + (((b << 14) + (gy << 7) + gx) << 3);
  *reinterpret_cast<float4*>(op) = make_float4(ov[0], ov[1], ov[2], ov[3]);
  *reinterpret_cast<float4*>(op + 4) = make_float4(ov[4], ov[5], ov[6], ov[7]);
}

// shortcut 3x3 conv + bn2 + relu, NCHW in (16 ch, 256^2), scalar staging.
__global__ __launch_bounds__(256, 4) void k_conv3s(
    const float* __restrict__ xin,
    const float* __restrict__ wgt, const float* __restrict__ bias,
    const float* __restrict__ bng, const float* __restrict__ bnb,
    const float* __restrict__ bnm, const float* __restrict__ bnv,
    float* __restrict__ out) {
  int bx = blockIdx.x << 5, by = blockIdx.y << 5, b = blockIdx.z;
  int t = threadIdx.x;
  int py = t >> 3, px0 = (t & 7) << 2;
  __shared__ __align__(16) float4 xt[34 * 35];
  __shared__ __align__(16) float4 wt[4 * 9 * 8];
  for (int idx = t; idx < 288; idx += 256) {
    int g = idx / 72, rem = idx - g * 72;
    int tap = rem >> 3, o = rem & 7;
    int ky = tap / 3, kx = tap - ky * 3;
    float4 wv;
    wv.x = wgt[((o * 16 + g * 4 + 0) * 3 + ky) * 3 + kx];
    wv.y = wgt[((o * 16 + g * 4 + 1) * 3 + ky) * 3 + kx];
    wv.z = wgt[((o * 16 + g * 4 + 2) * 3 + ky) * 3 + kx];
    wv.w = wgt[((o * 16 + g * 4 + 3) * 3 + ky) * 3 + kx];
    wt[idx] = wv;
  }
  float acc[4][8];
#pragma unroll
  for (int i = 0; i < 4; ++i)
#pragma unroll
    for (int o = 0; o < 8; ++o) acc[i][o] = 0.f;

  float4 sr[5];
  auto loadg = [&](int g) {
#pragma unroll
    for (int k = 0; k < 5; ++k) {
      int i = t + (k << 8);
      float4 v = make_float4(0.f, 0.f, 0.f, 0.f);
      if (i < 1156) {
        int r = i / 34, c = i - r * 34;
        int gy = by - 1 + r, gx = bx - 1 + c;
        if ((unsigned)gy < 256u && (unsigned)gx < 256u) {
          const float* p0 = xin + (((b * 16 + (g << 2)) << 8) + gy) * 256 + gx;
          v.x = p0[0]; v.y = p0[65536]; v.z = p0[131072]; v.w = p0[196608];
        }
      }
      sr[k] = v;
    }
  };
  auto writeg = [&]() {
#pragma unroll
    for (int k = 0; k < 5; ++k) {
      int i = t + (k << 8);
      if (i < 1156) {
        int r = i / 34;
        xt[r * 35 + (i - r * 34)] = sr[k];
      }
    }
  };

  loadg(0);
#pragma unroll 1
  for (int g = 0; g < 4; ++g) {
    writeg();
    __syncthreads();
    if (g < 3) loadg(g + 1);
#pragma unroll
    for (int ky = 0; ky < 3; ++ky) {
      float4 xr[6];
#pragma unroll
      for (int q = 0; q < 6; ++q) xr[q] = xt[(py + ky) * 35 + px0 + q];
#pragma unroll
      for (int kx = 0; kx < 3; ++kx)
#pragma unroll
        for (int o = 0; o < 8; ++o) {
          float4 wv = wt[(g * 9 + ky * 3 + kx) * 8 + o];
#pragma unroll
          for (int i = 0; i < 4; ++i) {
            float4 xv = xr[kx + i];
            acc[i][o] = fmaf(xv.w, wv.w, fmaf(xv.z, wv.z, fmaf(xv.y, wv.y, fmaf(xv.x, wv.x, acc[i][o]))));
          }
        }
    }
    __syncthreads();
  }
  float scl[8], sbs[8];
#pragma unroll
  for (int o = 0; o < 8; ++o) {
    float rs = rsqrtf(bnv[o] + 1e-5f) * bng[o];
    scl[o] = rs;
    sbs[o] = (bias[o] - bnm[o]) * rs + bnb[o];
  }
  int gy = by + py;
#pragma unroll
  for (int i = 0; i < 4; ++i) {
    int gx = bx + px0 + i;
    float ov[8];
#pragma unroll
    for (int o = 0; o < 8; ++o)
      ov[o] = fmaxf(acc[i][o] * scl[o] + sbs[o], 0.f);
    float* op = out + (((b << 16) + (gy << 8) + gx) << 3);
    *reinterpret_cast<float4*>(op) = make_float4(ov[0], ov[1], ov[2], ov[3]);
    *reinterpret_cast<float4*>(op + 4) = make_float4(ov[4], ov[5], ov[6], ov[7]);
  }
}

// last 3x3 conv: on-the-fly bilinear-2x of E (groups 0,1) + D (groups 2,3).
__global__ __launch_bounds__(256, 3) void k_lastup(
    const float* __restrict__ E, const float* __restrict__ D,
    const float* __restrict__ wgt, const float* __restrict__ bias,
    float* __restrict__ out) {
  int bx = blockIdx.x << 5, by = blockIdx.y << 5, b = blockIdx.z;
  int t = threadIdx.x;
  int py = t >> 3, px0 = (t & 7) << 2;
  __shared__ __align__(16) float4 et[19][22][2];
  __shared__ __align__(16) float4 xt[34 * 35];
  __shared__ __align__(16) float4 wt[144];
  for (int idx = t; idx < 144; idx += 256) {
    int g = idx / 36, rem = idx - g * 36;
    int tap = rem >> 2, o = rem & 3;
    int ky = tap / 3, kx = tap - ky * 3;
    float4 wv;
    wv.x = wgt[((o * 16 + g * 4 + 0) * 3 + ky) * 3 + kx];
    wv.y = wgt[((o * 16 + g * 4 + 1) * 3 + ky) * 3 + kx];
    wv.z = wgt[((o * 16 + g * 4 + 2) * 3 + ky) * 3 + kx];
    wv.w = wgt[((o * 16 + g * 4 + 3) * 3 + ky) * 3 + kx];
    wt[idx] = wv;
  }
  float acc[4][4];
#pragma unroll
  for (int i = 0; i < 4; ++i)
#pragma unroll
    for (int o = 0; o < 4; ++o) acc[i][o] = 0.f;

  float4 dreg[5];
  auto loadD = [&](int h) {
#pragma unroll
    for (int k = 0; k < 5; ++k) {
      int i = t + (k << 8);
      float4 v = make_float4(0.f, 0.f, 0.f, 0.f);
      if (i < 1156) {
        int r = i / 34, c = i - r * 34;
        int gy = by - 1 + r, gx = bx - 1 + c;
        if ((unsigned)gy < 256u && (unsigned)gx < 256u)
          v = *reinterpret_cast<const float4*>(
              D + (((b << 16) + (gy << 8) + gx) << 3) + (h << 2));
      }
      dreg[k] = v;
    }
  };
  auto compute = [&](int g) {
#pragma unroll
    for (int ky = 0; ky < 3; ++ky) {
      float4 xr[6];
#pragma unroll
      for (int q = 0; q < 6; ++q) xr[q] = xt[(py + ky) * 35 + px0 + q];
#pragma unroll
      for (int kx = 0; kx < 3; ++kx)
#pragma unroll
        for (int o = 0; o < 4; ++o) {
          float4 wv = wt[(g * 9 + ky * 3 + kx) * 4 + o];
#pragma unroll
          for (int i = 0; i < 4; ++i) {
            float4 xv = xr[kx + i];
            acc[i][o] = fmaf(xv.w, wv.w, fmaf(xv.z, wv.z, fmaf(xv.y, wv.y, fmaf(xv.x, wv.x, acc[i][o]))));
          }
        }
    }
  };

  loadD(0);
  int ey0 = (by >> 1) - 1, ex0 = (bx >> 1) - 3;
#pragma unroll
  for (int k = 0; k < 4; ++k) {
    int i = t + (k << 8);
    if (i < 836) {
      int h = i & 1, q = i >> 1;
      int r = q / 22, c = q - r * 22;
      int er = min(max(ey0 + r, 0), 127), ec = min(max(ex0 + c, 0), 127);
      et[r][c][h] = *reinterpret_cast<const float4*>(
          E + (((b << 14) + (er << 7) + ec) << 3) + (h << 2));
    }
  }
#pragma unroll 1
  for (int h = 0; h < 2; ++h) {
    __syncthreads();
#pragma unroll
    for (int k = 0; k < 5; ++k) {
      int i = t + (k << 8);
      if (i < 1156) {
        int r = i / 34;
        xt[r * 35 + (i - r * 34)] = dreg[k];
      }
    }
    __syncthreads();
    if (h == 0) loadD(1);
    compute(2 + h);
  }
#pragma unroll 1
  for (int h = 0; h < 2; ++h) {
    __syncthreads();
#pragma unroll
    for (int k = 0; k < 5; ++k) {
      int i = t + (k << 8);
      if (i < 1156) {
        int r = i / 34, c = i - r * 34;
        int gy = by - 1 + r, gx = bx - 1 + c;
        float4 uv = make_float4(0.f, 0.f, 0.f, 0.f);
        if ((unsigned)gy < 256u && (unsigned)gx < 256u) {
          int r0 = (gy - 1) >> 1, c0 = (gx - 1) >> 1;
          float fy = (gy & 1) ? 0.25f : 0.75f;
          float fx = (gx & 1) ? 0.25f : 0.75f;
          int ra = max(r0, 0) - ey0, rb = min(r0 + 1, 127) - ey0;
          int ca = max(c0, 0) - ex0, cb = min(c0 + 1, 127) - ex0;
          float w00 = (1.f - fy) * (1.f - fx), w01 = (1.f - fy) * fx;
          float w10 = fy * (1.f - fx), w11 = fy * fx;
          float4 a = et[ra][ca][h], bq = et[ra][cb][h];
          float4 cq = et[rb][ca][h], dq = et[rb][cb][h];
          uv.x = w00 * a.x + w01 * bq.x + w10 * cq.x + w11 * dq.x;
          uv.y = w00 * a.y + w01 * bq.y + w10 * cq.y + w11 * dq.y;
          uv.z = w00 * a.z + w01 * bq.z + w10 * cq.z + w11 * dq.z;
          uv.w = w00 * a.w + w01 * bq.w + w10 * cq.w + w11 * dq.w;
        }
        xt[r * 35 + c] = uv;
      }
    }
    __syncthreads();
    compute(h);
  }
  float b0 = bias[0], b1v = bias[1], b2v = bias[2], b3v = bias[3];
  int gy = by + py;
#pragma unroll
  for (int i = 0; i < 4; ++i) {
    int gx = bx + px0 + i;
    float* op = out + (((b << 16) + (gy << 8) + gx) << 2);
    *reinterpret_cast<float4*>(op) = make_float4(acc[i][0] + b0, acc[i][1] + b1v,
                                                 acc[i][2] + b2v, acc[i][3] + b3v);
  }
}

// bilinear 2x (256->512, zero outside) + 5x5 conv pad 2 + sigmoid -> out1
__global__ __launch_bounds__(256, 3) void k_final(
    const float* __restrict__ v4, const float* __restrict__ w5,
    const float* __restrict__ b5, float* __restrict__ out) {
  int bx = blockIdx.x << 5, by = blockIdx.y << 5, b = blockIdx.z;
  int t = threadIdx.x;
  __shared__ __align__(16) float4 vt[20 * 21];
  __shared__ __align__(16) float4 ut[36 * 37];
  __shared__ __align__(16) float4 w5s[25];
  if (t < 25) {
    w5s[t] = make_float4(w5[t], w5[25 + t], w5[50 + t], w5[75 + t]);
  }
  int vy0 = (by >> 1) - 2, vx0 = (bx >> 1) - 2;
  for (int i = t; i < 400; i += 256) {
    int r = i / 20, c = i - r * 20;
    int gy = vy0 + r, gx = vx0 + c;
    float4 v = make_float4(0.f, 0.f, 0.f, 0.f);
    if (gy >= 0 && gy < 256 && gx >= 0 && gx < 256)
      v = *reinterpret_cast<const float4*>(v4 + ((b << 16) + gy * 256 + gx) * 4);
    vt[r * 21 + c] = v;
  }
  __syncthreads();
  for (int i = t; i < 36 * 36; i += 256) {
    int r = i / 36, c = i - r * 36;
    int yy = by - 2 + r, xx = bx - 2 + c;
    float4 uv = make_float4(0.f, 0.f, 0.f, 0.f);
    if (yy >= 0 && yy < 512 && xx >= 0 && xx < 512) {
      int r0 = (yy - 1) >> 1, c0 = (xx - 1) >> 1;
      float fy = (yy & 1) ? 0.25f : 0.75f;
      float fx = (xx & 1) ? 0.25f : 0.75f;
      int ra = max(r0, 0) - vy0, rb = min(r0 + 1, 255) - vy0;
      int ca = max(c0, 0) - vx0, cb = min(c0 + 1, 255) - vx0;
      float4 a = vt[ra * 21 + ca], bq = vt[ra * 21 + cb];
      float4 cq = vt[rb * 21 + ca], dq = vt[rb * 21 + cb];
      float w00 = (1.f - fy) * (1.f - fx), w01 = (1.f - fy) * fx;
      float w10 = fy * (1.f - fx), w11 = fy * fx;
      uv.x = w00 * a.x + w01 * bq.x + w10 * cq.x + w11 * dq.x;
      uv.y = w00 * a.y + w01 * bq.y + w10 * cq.y + w11 * dq.y;
      uv.z = w00 * a.z + w01 * bq.z + w10 * cq.z + w11 * dq.z;
      uv.w = w00 * a.w + w01 * bq.w + w10 * cq.w + w11 * dq.w;
    }
    ut[r * 37 + c] = uv;
  }
  __syncthreads();
  float bb = b5[0];
  int py = t >> 3, px0 = (t & 7) << 2;
  float a0 = bb, a1 = bb, a2 = bb, a3 = bb;
#pragma unroll
  for (int ky = 0; ky < 5; ++ky) {
    float4 xr[8];
#pragma unroll
    for (int q = 0; q < 8; ++q) xr[q] = ut[(py + ky) * 37 + px0 + q];
#pragma unroll
    for (int kx = 0; kx < 5; ++kx) {
      float4 w = w5s[ky * 5 + kx];
      float4 x0 = xr[kx], x1 = xr[kx + 1], x2 = xr[kx + 2], x3 = xr[kx + 3];
      a0 = fmaf(x0.w, w.w, fmaf(x0.z, w.z, fmaf(x0.y, w.y, fmaf(x0.x, w.x, a0))));
      a1 = fmaf(x1.w, w.w, fmaf(x1.z, w.z, fmaf(x1.y, w.y, fmaf(x1.x, w.x, a1))));
      a2 = fmaf(x2.w, w.w, fmaf(x2.z, w.z, fmaf(x2.y, w.y, fmaf(x2.x, w.x, a2))));
      a3 = fmaf(x3.w, w.w, fmaf(x3.z, w.z, fmaf(x3.y, w.y, fmaf(x3.x, w.x, a3))));
    }
  }
  int oy = by + py, ox = bx + px0;
  nt_store4(out + (b << 18) + oy * 512 + ox,
            1.f / (1.f + __expf(-a0)), 1.f / (1.f + __expf(-a1)),
            1.f / (1.f + __expf(-a2)), 1.f / (1.f + __expf(-a3)));
}

extern "C" void kernel_launch(void* const* d_in, const int* in_sizes, int n_in,
                              void* d_out, int out_size, void* d_ws, size_t ws_size,
                              hipStream_t stream) {
  (void)in_sizes; (void)n_in; (void)out_size; (void)ws_size;
  const float* feats4x = (const float*)d_in[0];
  const float* feats2x = (const float*)d_in[1];
  const float* clg     = (const float*)d_in[2];
  const float* dw_w    = (const float*)d_in[3];
  const float* dw_b    = (const float*)d_in[4];
  const float* ln_g    = (const float*)d_in[5];
  const float* ln_b    = (const float*)d_in[6];
  const float* pw1_w   = (const float*)d_in[7];
  const float* pw1_b   = (const float*)d_in[8];
  const float* grn_g   = (const float*)d_in[9];
  const float* grn_b   = (const float*)d_in[10];
  const float* pw2_w   = (const float*)d_in[11];
  const float* pw2_b   = (const float*)d_in[12];
  const float* up_w    = (const float*)d_in[13];
  const float* up_b    = (const float*)d_in[14];
  const float* bn1_g   = (const float*)d_in[15];
  const float* bn1_b   = (const float*)d_in[16];
  const float* bn1_m   = (const float*)d_in[17];
  const float* bn1_v   = (const float*)d_in[18];
  const float* sh_w    = (const float*)d_in[19];
  const float* sh_b    = (const float*)d_in[20];
  const float* bn2_g   = (const float*)d_in[21];
  const float* bn2_b   = (const float*)d_in[22];
  const float* bn2_m   = (const float*)d_in[23];
  const float* bn2_v   = (const float*)d_in[24];
  const float* last_w  = (const float*)d_in[25];
  const float* last_b  = (const float*)d_in[26];
  const float* last2_w = (const float*)d_in[27];
  const float* last2_b = (const float*)d_in[28];
  float* outp = (float*)d_out;
  float* ws = (float*)d_ws;
  float* A      = ws;                      // lastup out (v4, 256^2)
  float* y1c    = ws + 8388608;            // 421888
  float* xact   = ws + 8810496;            // 421888
  int*   actIdx = (int*)(ws + 9232384);    // 13184
  int*   n_act  = (int*)(ws + 9245568);    // 16
  float* D      = ws + 16777216;           // shortcut branch (NHWC8 256^2)
  float* E      = ws + 25165824;           // up-conv out (NHWC8 128^2)
  float* gss    = ws + 27262976;           // 512
  float* w2sT   = gss + 512;               // 16384
  float* bias2  = w2sT + 16384;            // 512
  float* Kconst = bias2 + 512;             // 512

  hipMemsetAsync(gss, 0, 512 * sizeof(float), stream);
  k_sig<<<1024, 256, 0, stream>>>(clg, outp + 4194304);
  k_topk<<<16, 1024, 0, stream>>>(clg, actIdx, n_act);
  k_dws<<<dim3(103, 16), 256, 0, stream>>>(feats4x, actIdx, n_act, dw_w, dw_b,
                                           ln_g, ln_b, pw1_w, pw1_b, y1c, gss);
  k_grn<<<16, 256, 0, stream>>>(gss, n_act, grn_g, grn_b, pw2_w, pw2_b, pw1_b,
                                w2sT, bias2, Kconst);
  k_pw2s<<<dim3(103, 16), 256, 0, stream>>>(y1c, actIdx, n_act, w2sT, bias2,
                                            feats4x, xact);
  k_upconv<<<dim3(8, 8, 16), 256, 0, stream>>>(feats4x, Kconst, xact, actIdx,
                                               n_act, up_w, up_b, bn1_g, bn1_b,
                                               bn1_m, bn1_v, E);
  k_conv3s<<<dim3(8, 8, 16), 256, 0, stream>>>(feats2x, sh_w, sh_b, bn2_g,
                                               bn2_b, bn2_m, bn2_v, D);
  k_lastup<<<dim3(8, 8, 16), 256, 0, stream>>>(E, D, last_w, last_b, A);
  k_final<<<dim3(16, 16, 16), 256, 0, stream>>>(A, last2_w, last2_b, outp);
}